// Round 2
// baseline (814.770 us; speedup 1.0000x reference)
//
#include <hip/hip_runtime.h>
#include <hip/hip_bf16.h>
#include <cstdint>
#include <cstddef>

// Problem constants
#define E_   8
#define H_   2048
#define I_   2816
#define T_   512
#define KK_  2
#define NPAIR (T_*KK_)     // 1024 (token,k) pairs

// GEMM tiling
#define TM   192           // one m-tile per expert w.h.p. (cnt ~ 128±11) -> weights read once
#define TN   64
#define BK   64
#define LDSA 72            // padded LDS row stride (bf16): 144B, 16B-aligned, conflict-free
#define MT_  3             // m-frags per wave (TM / 4 waves / 16)

typedef __attribute__((ext_vector_type(8))) short          bf16x8;
typedef __attribute__((ext_vector_type(4))) float          f32x4;
typedef __attribute__((ext_vector_type(4))) unsigned short u16x4;

__device__ __forceinline__ unsigned short f2bf(float f){
  union { float f; unsigned u; } a; a.f = f;
  unsigned u = a.u;
  unsigned r = u + 0x7fffu + ((u >> 16) & 1u);   // round-to-nearest-even
  return (unsigned short)(r >> 16);
}

// ---------------------------------------------------------------------------
// Routing: bucket 1024 (t,k) pairs by expert. One block, 1024 threads.
// ---------------------------------------------------------------------------
__global__ void route_kernel(const int* __restrict__ ids, const float* __restrict__ w,
                             int* __restrict__ offs, int* __restrict__ ptok,
                             float* __restrict__ pw){
  __shared__ int scnt[E_];
  __shared__ int scur[E_];
  const int tid = threadIdx.x;            // 0..1023
  if (tid < E_) scnt[tid] = 0;
  __syncthreads();
  const int e = ids[tid];
  atomicAdd(&scnt[e], 1);
  __syncthreads();
  if (tid == 0){
    int s = 0;
    for (int i = 0; i < E_; i++){ offs[i] = s; scur[i] = s; s += scnt[i]; }
    offs[E_] = s;
  }
  __syncthreads();
  const int pos = atomicAdd(&scur[e], 1);
  ptok[pos] = tid >> 1;                   // token index
  pw[pos]   = w[tid];                     // router weight
}

// ---------------------------------------------------------------------------
// GEMM1: per expert, act[m,i] = silu(x@Wg^T) * (x@Wu^T); dequant folded into
// B staging (fp32 * scale -> bf16). grid: (I/TN=44, ceil(NPAIR/TM)=6, E=8)
// ---------------------------------------------------------------------------
__global__ __launch_bounds__(256, 2)
void gemm1_kernel(const float* __restrict__ x, const float* __restrict__ w13,
                  const float* __restrict__ s13, const int* __restrict__ offs,
                  const int* __restrict__ ptok, unsigned short* __restrict__ act)
{
  const int e   = blockIdx.z;
  const int off = offs[e];
  const int cnt = offs[e+1] - off;
  const int m0  = blockIdx.y * TM;
  if (m0 >= cnt) return;
  const int rows = min(TM, cnt - m0);
  const int nb   = blockIdx.x * TN;       // i-base within [0, I)

  __shared__ __align__(16) unsigned short As[TM][LDSA];        // 27648 B
  __shared__ __align__(16) unsigned short Bs[2*TN][LDSA];      // 18432 B (gate rows 0..63, up 64..127)

  const int tid  = threadIdx.x;
  const int wave = tid >> 6;
  const int lane = tid & 63;
  const int quad = lane >> 4;
  const int l16  = lane & 15;

  const float* w13e = w13 + (size_t)e * (2*I_) * H_;
  const float* s13e = s13 + (size_t)e * (2*I_/128) * (H_/128);

  // Per-thread staging maps (256 is a multiple of 16 -> f4 is tid-constant)
  const int f4   = tid & 15;              // float4 column 0..15 (BK=64 floats)
  const int rbase = tid >> 4;             // 0..15

  // A: 12 rows/thread (rbase + 16t), precompute x row pointers
  const float* aptr[12];
  #pragma unroll
  for (int t = 0; t < 12; t++){
    const int row = rbase + t*16;         // 0..191
    aptr[t] = (row < rows) ? (x + (size_t)ptok[off + m0 + row] * H_) : nullptr;
  }
  // B: 8 rows/thread (gate+up), precompute weight row pointers + scale rows
  const float* bptr[8];
  int bsrow[8];
  #pragma unroll
  for (int t = 0; t < 8; t++){
    const int r  = rbase + t*16;          // 0..127
    const int gr = (r >> 6)*I_ + nb + (r & 63);
    bptr[t]  = w13e + (size_t)gr * H_;
    bsrow[t] = (gr >> 7)*(H_/128);
  }

  f32x4 acc[2][MT_][4];
  #pragma unroll
  for (int h = 0; h < 2; h++)
    #pragma unroll
    for (int mt = 0; mt < MT_; mt++)
      #pragma unroll
      for (int nt = 0; nt < 4; nt++)
        acc[h][mt][nt] = (f32x4){0.f, 0.f, 0.f, 0.f};

  for (int kb = 0; kb < H_; kb += BK){
    // ---- stage A (x rows, fp32 -> bf16) ----
    #pragma unroll
    for (int t = 0; t < 12; t++){
      const int row = rbase + t*16;
      u16x4 v4 = (u16x4){0,0,0,0};
      if (aptr[t]){
        float4 v = *(const float4*)(aptr[t] + kb + f4*4);
        v4.x = f2bf(v.x); v4.y = f2bf(v.y); v4.z = f2bf(v.z); v4.w = f2bf(v.w);
      }
      *(u16x4*)&As[row][f4*4] = v4;
    }
    // ---- stage B (w13 rows, fp32 * scale -> bf16) ----
    #pragma unroll
    for (int t = 0; t < 8; t++){
      const int r = rbase + t*16;
      const float s = s13e[bsrow[t] + (kb >> 7)];
      float4 v = *(const float4*)(bptr[t] + kb + f4*4);
      u16x4 v4;
      v4.x = f2bf(v.x*s); v4.y = f2bf(v.y*s); v4.z = f2bf(v.z*s); v4.w = f2bf(v.w*s);
      *(u16x4*)&Bs[r][f4*4] = v4;
    }
    __syncthreads();

    // ---- MFMA ----
    #pragma unroll
    for (int kk = 0; kk < BK; kk += 32){
      bf16x8 af[MT_];
      #pragma unroll
      for (int mt = 0; mt < MT_; mt++)
        af[mt] = *(const bf16x8*)&As[wave*48 + mt*16 + l16][kk + quad*8];
      #pragma unroll
      for (int hh = 0; hh < 2; hh++){
        #pragma unroll
        for (int nt = 0; nt < 4; nt++){
          bf16x8 bfv = *(const bf16x8*)&Bs[hh*64 + nt*16 + l16][kk + quad*8];
          #pragma unroll
          for (int mt = 0; mt < MT_; mt++)
            acc[hh][mt][nt] = __builtin_amdgcn_mfma_f32_16x16x32_bf16(af[mt], bfv, acc[hh][mt][nt], 0, 0, 0);
        }
      }
    }
    __syncthreads();
  }

  // ---- epilogue: act = silu(gate)*up, write bf16 ----
  #pragma unroll
  for (int mt = 0; mt < MT_; mt++){
    #pragma unroll
    for (int nt = 0; nt < 4; nt++){
      #pragma unroll
      for (int r = 0; r < 4; r++){
        const int m = wave*48 + mt*16 + quad*4 + r;
        if (m < rows){
          const float g = acc[0][mt][nt][r];
          const float u = acc[1][mt][nt][r];
          const float sg = g / (1.f + __expf(-g));
          act[(size_t)(off + m0 + m)*I_ + (nb + nt*16 + l16)] = f2bf(sg * u);
        }
      }
    }
  }
}

// ---------------------------------------------------------------------------
// GEMM2: per expert, out[t,h] += coef * (act @ W2^T); dequant folded.
// grid: (H/TN=32, ceil(NPAIR/TM)=6, E=8)
// ---------------------------------------------------------------------------
__global__ __launch_bounds__(256, 2)
void gemm2_kernel(const unsigned short* __restrict__ act, const float* __restrict__ w2,
                  const float* __restrict__ s2, const int* __restrict__ offs,
                  const int* __restrict__ ptok, const float* __restrict__ pw,
                  float* __restrict__ out)
{
  const int e   = blockIdx.z;
  const int off = offs[e];
  const int cnt = offs[e+1] - off;
  const int m0  = blockIdx.y * TM;
  if (m0 >= cnt) return;
  const int rows = min(TM, cnt - m0);
  const int nb   = blockIdx.x * TN;       // h base

  __shared__ __align__(16) unsigned short As[TM][LDSA];        // 27648 B
  __shared__ __align__(16) unsigned short Bs[TN][LDSA];        //  9216 B

  const int tid  = threadIdx.x;
  const int wave = tid >> 6;
  const int lane = tid & 63;
  const int quad = lane >> 4;
  const int l16  = lane & 15;

  const float* w2e = w2 + (size_t)e * H_ * I_;
  const float* s2e = s2 + (size_t)e * (H_/128) * (I_/128);

  // A: bf16 rows, 8-elem chunks. ch is tid-constant; 6 rows/thread.
  const int ch  = tid & 7;                // chunk of 8 bf16 (BK=64)
  const int ar8 = tid >> 3;               // 0..31
  const unsigned short* aptr[6];
  #pragma unroll
  for (int t = 0; t < 6; t++){
    const int row = ar8 + t*32;           // 0..191
    aptr[t] = (row < rows) ? (act + (size_t)(off + m0 + row) * I_) : nullptr;
  }
  // B: 4 rows/thread
  const int f4    = tid & 15;
  const int rbase = tid >> 4;             // 0..15
  const float* bptr[4];
  int bsrow[4];
  #pragma unroll
  for (int t = 0; t < 4; t++){
    const int gr = nb + rbase + t*16;     // 0..2047
    bptr[t]  = w2e + (size_t)gr * I_;
    bsrow[t] = (gr >> 7)*(I_/128);
  }

  f32x4 acc[MT_][4];
  #pragma unroll
  for (int mt = 0; mt < MT_; mt++)
    #pragma unroll
    for (int nt = 0; nt < 4; nt++)
      acc[mt][nt] = (f32x4){0.f, 0.f, 0.f, 0.f};

  for (int kb = 0; kb < I_; kb += BK){
    // ---- stage A (act rows, already bf16) ----
    #pragma unroll
    for (int t = 0; t < 6; t++){
      const int row = ar8 + t*32;
      bf16x8 v = (bf16x8){0,0,0,0,0,0,0,0};
      if (aptr[t]) v = *(const bf16x8*)(aptr[t] + kb + ch*8);
      *(bf16x8*)&As[row][ch*8] = v;
    }
    // ---- stage B (w2 rows, fp32 * scale -> bf16) ----
    #pragma unroll
    for (int t = 0; t < 4; t++){
      const int r = rbase + t*16;
      const float s = s2e[bsrow[t] + (kb >> 7)];
      float4 v = *(const float4*)(bptr[t] + kb + f4*4);
      u16x4 v4;
      v4.x = f2bf(v.x*s); v4.y = f2bf(v.y*s); v4.z = f2bf(v.z*s); v4.w = f2bf(v.w*s);
      *(u16x4*)&Bs[r][f4*4] = v4;
    }
    __syncthreads();

    #pragma unroll
    for (int kk = 0; kk < BK; kk += 32){
      bf16x8 af[MT_];
      #pragma unroll
      for (int mt = 0; mt < MT_; mt++)
        af[mt] = *(const bf16x8*)&As[wave*48 + mt*16 + l16][kk + quad*8];
      #pragma unroll
      for (int nt = 0; nt < 4; nt++){
        bf16x8 bfv = *(const bf16x8*)&Bs[nt*16 + l16][kk + quad*8];
        #pragma unroll
        for (int mt = 0; mt < MT_; mt++)
          acc[mt][nt] = __builtin_amdgcn_mfma_f32_16x16x32_bf16(af[mt], bfv, acc[mt][nt], 0, 0, 0);
      }
    }
    __syncthreads();
  }

  // ---- epilogue: out[t, h] += coef * val ----
  #pragma unroll
  for (int mt = 0; mt < MT_; mt++){
    #pragma unroll
    for (int nt = 0; nt < 4; nt++){
      #pragma unroll
      for (int r = 0; r < 4; r++){
        const int m = wave*48 + mt*16 + quad*4 + r;
        if (m < rows){
          const int p = off + m0 + m;
          const float coef = pw[p];
          const int t = ptok[p];
          atomicAdd(&out[(size_t)t*H_ + nb + nt*16 + l16], coef * acc[mt][nt][r]);
        }
      }
    }
  }
}

// ---------------------------------------------------------------------------
extern "C" void kernel_launch(void* const* d_in, const int* in_sizes, int n_in,
                              void* d_out, int out_size, void* d_ws, size_t ws_size,
                              hipStream_t stream){
  const float* x   = (const float*)d_in[0];
  const int*   ids = (const int*)  d_in[1];
  const float* tw  = (const float*)d_in[2];
  const float* w13 = (const float*)d_in[3];
  const float* s13 = (const float*)d_in[4];
  const float* w2  = (const float*)d_in[5];
  const float* s2  = (const float*)d_in[6];
  float* out = (float*)d_out;

  // workspace layout
  char* ws = (char*)d_ws;
  int*   offs = (int*)ws;                               // 9 ints
  int*   ptok = (int*)(ws + 64);                        // 1024 ints
  float* pw   = (float*)(ws + 64 + NPAIR*4);            // 1024 floats
  unsigned short* act = (unsigned short*)(ws + 16384);  // [1024, I] bf16 = 5.77 MB

  hipMemsetAsync(d_out, 0, (size_t)T_*H_*sizeof(float), stream);
  route_kernel<<<1, NPAIR, 0, stream>>>(ids, tw, offs, ptok, pw);
  gemm1_kernel<<<dim3(I_/TN, (NPAIR + TM - 1)/TM, E_), 256, 0, stream>>>(x, w13, s13, offs, ptok, act);
  gemm2_kernel<<<dim3(H_/TN, (NPAIR + TM - 1)/TM, E_), 256, 0, stream>>>(act, w2, s2, offs, ptok, pw, out);
}

// Round 3
// 792.988 us; speedup vs baseline: 1.0275x; 1.0275x over previous
//
#include <hip/hip_runtime.h>
#include <hip/hip_bf16.h>
#include <cstdint>
#include <cstddef>

// Problem constants
#define E_   8
#define H_   2048
#define I_   2816
#define T_   512
#define NPAIR 1024         // T*K (token,k) pairs

// GEMM tiling
#define TM   192           // one m-tile per expert w.h.p. -> weights streamed once
#define TN   32            // small n-tile -> 704/512 live blocks (occupancy)
#define BK   64
#define LDSB 72            // padded LDS row stride (bf16): 144 B
#define MT_  3             // m-frags per wave (192 / 4 waves / 16)

typedef __attribute__((ext_vector_type(8))) short          bf16x8;
typedef __attribute__((ext_vector_type(4))) float          f32x4;
typedef __attribute__((ext_vector_type(8))) unsigned short u16x8;

__device__ __forceinline__ unsigned short f2bf(float f){
  union { float f; unsigned u; } a; a.f = f;
  unsigned u = a.u;
  unsigned r = u + 0x7fffu + ((u >> 16) & 1u);   // round-to-nearest-even
  return (unsigned short)(r >> 16);
}

// ---------------------------------------------------------------------------
// Routing: bucket 1024 (t,k) pairs by expert; also inverse map slot-of-pair.
// ---------------------------------------------------------------------------
__global__ void route_kernel(const int* __restrict__ ids,
                             int* __restrict__ offs, int* __restrict__ ptok,
                             int* __restrict__ sop){
  __shared__ int scnt[E_];
  __shared__ int scur[E_];
  const int tid = threadIdx.x;            // 0..1023
  if (tid < E_) scnt[tid] = 0;
  __syncthreads();
  const int e = ids[tid];
  atomicAdd(&scnt[e], 1);
  __syncthreads();
  if (tid == 0){
    int s = 0;
    for (int i = 0; i < E_; i++){ offs[i] = s; scur[i] = s; s += scnt[i]; }
    offs[E_] = s;
  }
  __syncthreads();
  const int pos = atomicAdd(&scur[e], 1);
  ptok[pos] = tid >> 1;                   // token index for slot pos
  sop[tid]  = pos;                        // slot of pair tid
}

// ---------------------------------------------------------------------------
// Prep: gather+convert x rows into slot order, bf16. xg[slot][H]
// grid: (NPAIR), block: 256 (each thread 8 elems)
// ---------------------------------------------------------------------------
__global__ void prep_kernel(const float* __restrict__ x, const int* __restrict__ ptok,
                            unsigned short* __restrict__ xg){
  const int slot = blockIdx.x;
  const int tok  = ptok[slot];
  const int k0   = threadIdx.x * 8;
  const float4 v0 = *(const float4*)(x + (size_t)tok*H_ + k0);
  const float4 v1 = *(const float4*)(x + (size_t)tok*H_ + k0 + 4);
  u16x8 o;
  o[0]=f2bf(v0.x); o[1]=f2bf(v0.y); o[2]=f2bf(v0.z); o[3]=f2bf(v0.w);
  o[4]=f2bf(v1.x); o[5]=f2bf(v1.y); o[6]=f2bf(v1.z); o[7]=f2bf(v1.w);
  *(u16x8*)(xg + (size_t)slot*H_ + k0) = o;
}

// ---------------------------------------------------------------------------
// GEMM1: act[slot, i] = silu(x@Wg^T) * (x@Wu^T). A-frags direct from global
// (xg, L2-hot); B (weights) reg-prefetched + LDS double-buffered, dequant
// folded into staging. grid: (I/TN=88, 6, E=8), block 256.
// ---------------------------------------------------------------------------
__global__ __launch_bounds__(256, 3)
void gemm1_kernel(const unsigned short* __restrict__ xg, const float* __restrict__ w13,
                  const float* __restrict__ s13, const int* __restrict__ offs,
                  unsigned short* __restrict__ act)
{
  const int e   = blockIdx.z;
  const int off = offs[e];
  const int cnt = offs[e+1] - off;
  const int m0  = blockIdx.y * TM;
  if (m0 >= cnt) return;
  const int rows = min(TM, cnt - m0);
  const int nb   = blockIdx.x * TN;       // i-base

  __shared__ __align__(16) unsigned short Bs[2][2*TN][LDSB];  // 18432 B

  const int tid  = threadIdx.x;
  const int wave = tid >> 6;
  const int lane = tid & 63;
  const int quad = lane >> 4;
  const int l16  = lane & 15;

  const float* w13e = w13 + (size_t)e * (2*I_) * H_;
  const float* s13e = s13 + (size_t)e * (2*I_/128) * (H_/128);

  // B staging: row br (0..63: gate 0..31, up 32..63), 4 threads/row, 16 floats each
  const int br = tid >> 2;
  const int bc = tid & 3;                 // f4 group: f4 = bc*4+j (16 contiguous floats)
  const int grow = (br < TN) ? (nb + br) : (I_ + nb + (br - TN));
  const float* bp = w13e + (size_t)grow * H_;
  const int srow  = ((br < TN) ? 0 : (I_/128)) + (nb >> 7);  // scale row (stride H/128)

  // A fragment row pointers (clamped for buffer safety; OOB rows discarded)
  const unsigned short* aP[MT_];
  #pragma unroll
  for (int mt = 0; mt < MT_; mt++){
    int sl = off + m0 + wave*(TM/4) + mt*16 + l16;
    sl = min(sl, NPAIR - 1);
    aP[mt] = xg + (size_t)sl * H_;
  }

  f32x4 acc[2][MT_][2];
  #pragma unroll
  for (int h = 0; h < 2; h++)
    #pragma unroll
    for (int mt = 0; mt < MT_; mt++)
      #pragma unroll
      for (int nt = 0; nt < 2; nt++)
        acc[h][mt][nt] = (f32x4){0.f, 0.f, 0.f, 0.f};

  // prologue: stage kb=0 into Bs[0]
  float4 pb[4];
  #pragma unroll
  for (int j = 0; j < 4; j++) pb[j] = *(const float4*)(bp + (bc*4 + j)*4);
  {
    const float s = s13e[srow*(H_/128)];
    u16x8 wv0, wv1;
    wv0[0]=f2bf(pb[0].x*s); wv0[1]=f2bf(pb[0].y*s); wv0[2]=f2bf(pb[0].z*s); wv0[3]=f2bf(pb[0].w*s);
    wv0[4]=f2bf(pb[1].x*s); wv0[5]=f2bf(pb[1].y*s); wv0[6]=f2bf(pb[1].z*s); wv0[7]=f2bf(pb[1].w*s);
    wv1[0]=f2bf(pb[2].x*s); wv1[1]=f2bf(pb[2].y*s); wv1[2]=f2bf(pb[2].z*s); wv1[3]=f2bf(pb[2].w*s);
    wv1[4]=f2bf(pb[3].x*s); wv1[5]=f2bf(pb[3].y*s); wv1[6]=f2bf(pb[3].z*s); wv1[7]=f2bf(pb[3].w*s);
    *(u16x8*)&Bs[0][br][bc*16]     = wv0;
    *(u16x8*)&Bs[0][br][bc*16 + 8] = wv1;
  }
  __syncthreads();

  int cur = 0;
  for (int kb = 0; kb < H_; kb += BK){
    const bool more = (kb + BK) < H_;
    if (more){
      #pragma unroll
      for (int j = 0; j < 4; j++) pb[j] = *(const float4*)(bp + kb + BK + (bc*4 + j)*4);
    }
    // A fragments (global, L2-hot; no barrier dependency)
    bf16x8 af[2][MT_];
    #pragma unroll
    for (int kk = 0; kk < 2; kk++)
      #pragma unroll
      for (int mt = 0; mt < MT_; mt++)
        af[kk][mt] = *(const bf16x8*)(aP[mt] + kb + kk*32 + quad*8);

    #pragma unroll
    for (int kk = 0; kk < 2; kk++){
      #pragma unroll
      for (int hh = 0; hh < 2; hh++){
        #pragma unroll
        for (int nt = 0; nt < 2; nt++){
          bf16x8 bv = *(const bf16x8*)&Bs[cur][hh*TN + nt*16 + l16][kk*32 + quad*8];
          #pragma unroll
          for (int mt = 0; mt < MT_; mt++)
            acc[hh][mt][nt] = __builtin_amdgcn_mfma_f32_16x16x32_bf16(af[kk][mt], bv, acc[hh][mt][nt], 0, 0, 0);
        }
      }
    }
    if (more){
      const float s = s13e[srow*(H_/128) + ((kb + BK) >> 7)];
      u16x8 wv0, wv1;
      wv0[0]=f2bf(pb[0].x*s); wv0[1]=f2bf(pb[0].y*s); wv0[2]=f2bf(pb[0].z*s); wv0[3]=f2bf(pb[0].w*s);
      wv0[4]=f2bf(pb[1].x*s); wv0[5]=f2bf(pb[1].y*s); wv0[6]=f2bf(pb[1].z*s); wv0[7]=f2bf(pb[1].w*s);
      wv1[0]=f2bf(pb[2].x*s); wv1[1]=f2bf(pb[2].y*s); wv1[2]=f2bf(pb[2].z*s); wv1[3]=f2bf(pb[2].w*s);
      wv1[4]=f2bf(pb[3].x*s); wv1[5]=f2bf(pb[3].y*s); wv1[6]=f2bf(pb[3].z*s); wv1[7]=f2bf(pb[3].w*s);
      *(u16x8*)&Bs[cur^1][br][bc*16]     = wv0;
      *(u16x8*)&Bs[cur^1][br][bc*16 + 8] = wv1;
      __syncthreads();
      cur ^= 1;
    }
  }

  // epilogue: act = silu(gate)*up
  #pragma unroll
  for (int mt = 0; mt < MT_; mt++){
    #pragma unroll
    for (int nt = 0; nt < 2; nt++){
      #pragma unroll
      for (int r = 0; r < 4; r++){
        const int m = wave*(TM/4) + mt*16 + quad*4 + r;
        if (m < rows){
          const float g = acc[0][mt][nt][r];
          const float u = acc[1][mt][nt][r];
          const float sg = g / (1.f + __expf(-g));
          act[(size_t)(off + m0 + m)*I_ + (nb + nt*16 + l16)] = f2bf(sg * u);
        }
      }
    }
  }
}

// ---------------------------------------------------------------------------
// GEMM2: buf[slot, h] = act @ W2^T (unscaled; combine applies router weight).
// grid: (H/TN=64, 6, E=8), block 256.
// ---------------------------------------------------------------------------
__global__ __launch_bounds__(256, 4)
void gemm2_kernel(const unsigned short* __restrict__ act, const float* __restrict__ w2,
                  const float* __restrict__ s2, const int* __restrict__ offs,
                  float* __restrict__ buf)
{
  const int e   = blockIdx.z;
  const int off = offs[e];
  const int cnt = offs[e+1] - off;
  const int m0  = blockIdx.y * TM;
  if (m0 >= cnt) return;
  const int rows = min(TM, cnt - m0);
  const int nb   = blockIdx.x * TN;       // h-base

  __shared__ __align__(16) unsigned short Bs[2][TN][LDSB];   // 9216 B

  const int tid  = threadIdx.x;
  const int wave = tid >> 6;
  const int lane = tid & 63;
  const int quad = lane >> 4;
  const int l16  = lane & 15;

  const float* w2e = w2 + (size_t)e * H_ * I_;
  const float* s2e = s2 + (size_t)e * (H_/128) * (I_/128);

  // B staging: 8 threads/row, 8 contiguous floats each
  const int br = tid >> 3;                // 0..31
  const int bc = tid & 7;                 // f4 = bc*2+j
  const float* bp = w2e + (size_t)(nb + br) * I_;
  const int srow  = nb >> 7;

  const unsigned short* aP[MT_];
  #pragma unroll
  for (int mt = 0; mt < MT_; mt++){
    int sl = off + m0 + wave*(TM/4) + mt*16 + l16;
    sl = min(sl, NPAIR - 1);
    aP[mt] = act + (size_t)sl * I_;
  }

  f32x4 acc[MT_][2];
  #pragma unroll
  for (int mt = 0; mt < MT_; mt++)
    #pragma unroll
    for (int nt = 0; nt < 2; nt++)
      acc[mt][nt] = (f32x4){0.f, 0.f, 0.f, 0.f};

  float4 pb[2];
  #pragma unroll
  for (int j = 0; j < 2; j++) pb[j] = *(const float4*)(bp + (bc*2 + j)*4);
  {
    const float s = s2e[srow*(I_/128)];
    u16x8 wv;
    wv[0]=f2bf(pb[0].x*s); wv[1]=f2bf(pb[0].y*s); wv[2]=f2bf(pb[0].z*s); wv[3]=f2bf(pb[0].w*s);
    wv[4]=f2bf(pb[1].x*s); wv[5]=f2bf(pb[1].y*s); wv[6]=f2bf(pb[1].z*s); wv[7]=f2bf(pb[1].w*s);
    *(u16x8*)&Bs[0][br][bc*8] = wv;
  }
  __syncthreads();

  int cur = 0;
  for (int kb = 0; kb < I_; kb += BK){
    const bool more = (kb + BK) < I_;
    if (more){
      #pragma unroll
      for (int j = 0; j < 2; j++) pb[j] = *(const float4*)(bp + kb + BK + (bc*2 + j)*4);
    }
    bf16x8 af[2][MT_];
    #pragma unroll
    for (int kk = 0; kk < 2; kk++)
      #pragma unroll
      for (int mt = 0; mt < MT_; mt++)
        af[kk][mt] = *(const bf16x8*)(aP[mt] + kb + kk*32 + quad*8);

    #pragma unroll
    for (int kk = 0; kk < 2; kk++){
      #pragma unroll
      for (int nt = 0; nt < 2; nt++){
        bf16x8 bv = *(const bf16x8*)&Bs[cur][nt*16 + l16][kk*32 + quad*8];
        #pragma unroll
        for (int mt = 0; mt < MT_; mt++)
          acc[mt][nt] = __builtin_amdgcn_mfma_f32_16x16x32_bf16(af[kk][mt], bv, acc[mt][nt], 0, 0, 0);
      }
    }
    if (more){
      const float s = s2e[srow*(I_/128) + ((kb + BK) >> 7)];
      u16x8 wv;
      wv[0]=f2bf(pb[0].x*s); wv[1]=f2bf(pb[0].y*s); wv[2]=f2bf(pb[0].z*s); wv[3]=f2bf(pb[0].w*s);
      wv[4]=f2bf(pb[1].x*s); wv[5]=f2bf(pb[1].y*s); wv[6]=f2bf(pb[1].z*s); wv[7]=f2bf(pb[1].w*s);
      *(u16x8*)&Bs[cur^1][br][bc*8] = wv;
      __syncthreads();
      cur ^= 1;
    }
  }

  // epilogue: plain stores per slot row (no atomics)
  #pragma unroll
  for (int mt = 0; mt < MT_; mt++){
    #pragma unroll
    for (int nt = 0; nt < 2; nt++){
      #pragma unroll
      for (int r = 0; r < 4; r++){
        const int m = wave*(TM/4) + mt*16 + quad*4 + r;
        if (m < rows)
          buf[(size_t)(off + m0 + m)*H_ + (nb + nt*16 + l16)] = acc[mt][nt][r];
      }
    }
  }
}

// ---------------------------------------------------------------------------
// Combine: out[t,:] = tw[2t]*buf[sop[2t],:] + tw[2t+1]*buf[sop[2t+1],:]
// grid: (T*H/4/256 = 1024), block 256; one float4 per thread.
// ---------------------------------------------------------------------------
__global__ void combine_kernel(const float* __restrict__ buf, const int* __restrict__ sop,
                               const float* __restrict__ tw, float* __restrict__ out){
  const int gid = blockIdx.x*256 + threadIdx.x;   // 0..262143
  const int t = gid >> 9;                         // H/4 = 512 float4 per row
  const int c = gid & 511;
  const int s0 = sop[2*t], s1 = sop[2*t+1];
  const float w0 = tw[2*t], w1 = tw[2*t+1];
  const float4 v0 = ((const float4*)buf)[(size_t)s0*(H_/4) + c];
  const float4 v1 = ((const float4*)buf)[(size_t)s1*(H_/4) + c];
  float4 o;
  o.x = w0*v0.x + w1*v1.x;
  o.y = w0*v0.y + w1*v1.y;
  o.z = w0*v0.z + w1*v1.z;
  o.w = w0*v0.w + w1*v1.w;
  ((float4*)out)[gid] = o;
}

// ---------------------------------------------------------------------------
extern "C" void kernel_launch(void* const* d_in, const int* in_sizes, int n_in,
                              void* d_out, int out_size, void* d_ws, size_t ws_size,
                              hipStream_t stream){
  const float* x   = (const float*)d_in[0];
  const int*   ids = (const int*)  d_in[1];
  const float* tw  = (const float*)d_in[2];
  const float* w13 = (const float*)d_in[3];
  const float* s13 = (const float*)d_in[4];
  const float* w2  = (const float*)d_in[5];
  const float* s2  = (const float*)d_in[6];
  float* out = (float*)d_out;

  // workspace layout (~13.8 MB): buf aliases xg (xg dead after gemm1)
  char* ws = (char*)d_ws;
  int* offs = (int*)ws;                                   // 9 ints
  int* ptok = (int*)(ws + 64);                            // 1024 ints
  int* sop  = (int*)(ws + 64 + 4096);                     // 1024 ints
  unsigned short* xg  = (unsigned short*)(ws + 16384);    // [1024][H] bf16 = 4 MB
  float*          buf = (float*)(ws + 16384);             // [1024][H] f32  = 8 MB (aliases xg)
  unsigned short* act = (unsigned short*)(ws + 16384 + (size_t)NPAIR*H_*4);  // [1024][I] bf16 = 5.77 MB

  route_kernel  <<<1, NPAIR, 0, stream>>>(ids, offs, ptok, sop);
  prep_kernel   <<<NPAIR, 256, 0, stream>>>(x, ptok, xg);
  gemm1_kernel  <<<dim3(I_/TN, (NPAIR + TM - 1)/TM, E_), 256, 0, stream>>>(xg, w13, s13, offs, act);
  gemm2_kernel  <<<dim3(H_/TN, (NPAIR + TM - 1)/TM, E_), 256, 0, stream>>>(act, w2, s2, offs, buf);
  combine_kernel<<<(T_*H_/4)/256, 256, 0, stream>>>(buf, sop, tw, out);
}

// Round 4
// 726.150 us; speedup vs baseline: 1.1220x; 1.0920x over previous
//
#include <hip/hip_runtime.h>
#include <hip/hip_bf16.h>
#include <cstdint>
#include <cstddef>

// Problem constants
#define E_   8
#define H_   2048
#define I_   2816
#define T_   512
#define NPAIR 1024         // T*K (token,k) pairs

// GEMM tiling
#define TM   192           // one m-tile per expert w.h.p. -> weights streamed once
#define TN   32
#define BK   64
#define LDSB 72            // padded LDS row stride (bf16): 144 B
#define MT_  3             // m-frags per wave (192 / 4 waves / 16)

typedef __attribute__((ext_vector_type(8))) short          bf16x8;
typedef __attribute__((ext_vector_type(4))) float          f32x4;
typedef __attribute__((ext_vector_type(8))) unsigned short u16x8;

__device__ __forceinline__ unsigned short f2bf(float f){
  union { float f; unsigned u; } a; a.f = f;
  unsigned u = a.u;
  unsigned r = u + 0x7fffu + ((u >> 16) & 1u);   // RNE
  return (unsigned short)(r >> 16);
}

// Pack 4 floats (x scale) to 4 bf16 via packed HW cvt where available
__device__ __forceinline__ void cvt4(u16x8& dst, int base, const float4 v, float s){
  __hip_bfloat162 p0 = __float22bfloat162_rn(float2{v.x*s, v.y*s});
  __hip_bfloat162 p1 = __float22bfloat162_rn(float2{v.z*s, v.w*s});
  union { __hip_bfloat162 b; unsigned u; } a0{p0}, a1{p1};
  dst[base+0] = (unsigned short)(a0.u & 0xffff);
  dst[base+1] = (unsigned short)(a0.u >> 16);
  dst[base+2] = (unsigned short)(a1.u & 0xffff);
  dst[base+3] = (unsigned short)(a1.u >> 16);
}

// LDS-only barrier: drain LDS ops, DO NOT drain vmcnt -> global prefetch
// loads stay in flight across the barrier (AITER/CK-style pipeline).
__device__ __forceinline__ void sync_lds(){
  asm volatile("s_waitcnt lgkmcnt(0)\n\ts_barrier" ::: "memory");
}

// ---------------------------------------------------------------------------
// Routing: bucket 1024 (t,k) pairs by expert; also inverse map slot-of-pair.
// ---------------------------------------------------------------------------
__global__ void route_kernel(const int* __restrict__ ids,
                             int* __restrict__ offs, int* __restrict__ ptok,
                             int* __restrict__ sop){
  __shared__ int scnt[E_];
  __shared__ int scur[E_];
  const int tid = threadIdx.x;
  if (tid < E_) scnt[tid] = 0;
  __syncthreads();
  const int e = ids[tid];
  atomicAdd(&scnt[e], 1);
  __syncthreads();
  if (tid == 0){
    int s = 0;
    for (int i = 0; i < E_; i++){ offs[i] = s; scur[i] = s; s += scnt[i]; }
    offs[E_] = s;
  }
  __syncthreads();
  const int pos = atomicAdd(&scur[e], 1);
  ptok[pos] = tid >> 1;
  sop[tid]  = pos;
}

// ---------------------------------------------------------------------------
// Prep: gather+convert x rows into slot order, bf16. xg[slot][H]
// ---------------------------------------------------------------------------
__global__ void prep_kernel(const float* __restrict__ x, const int* __restrict__ ptok,
                            unsigned short* __restrict__ xg){
  const int slot = blockIdx.x;
  const int tok  = ptok[slot];
  const int k0   = threadIdx.x * 8;
  const float4 v0 = *(const float4*)(x + (size_t)tok*H_ + k0);
  const float4 v1 = *(const float4*)(x + (size_t)tok*H_ + k0 + 4);
  u16x8 o;
  cvt4(o, 0, v0, 1.f);
  cvt4(o, 4, v1, 1.f);
  *(u16x8*)(xg + (size_t)slot*H_ + k0) = o;
}

// ---------------------------------------------------------------------------
// GEMM1: act[slot,i] = silu(x@Wg^T)*(x@Wu^T). B: global->reg prefetch
// distance 2 + LDS double-buffer (even tiles buf0, odd buf1); A: global
// direct, distance-1 reg prefetch. One LDS-only barrier per tile.
// grid: (I/TN=88, 6, E=8), block 256.
// ---------------------------------------------------------------------------
__global__ __launch_bounds__(256, 3)
void gemm1_kernel(const unsigned short* __restrict__ xg, const float* __restrict__ w13,
                  const float* __restrict__ s13, const int* __restrict__ offs,
                  unsigned short* __restrict__ act)
{
  const int e   = blockIdx.z;
  const int off = offs[e];
  const int cnt = offs[e+1] - off;
  const int m0  = blockIdx.y * TM;
  if (m0 >= cnt) return;
  const int rows = min(TM, cnt - m0);
  const int nb   = blockIdx.x * TN;

  __shared__ __align__(16) unsigned short Bs[2][2*TN][LDSB];  // 18432 B

  const int tid  = threadIdx.x;
  const int wave = tid >> 6;
  const int lane = tid & 63;
  const int quad = lane >> 4;
  const int l16  = lane & 15;

  const float* w13e = w13 + (size_t)e * (2*I_) * H_;
  const float* s13e = s13 + (size_t)e * (2*I_/128) * (H_/128);

  // B staging: row br (0..63: gate 0..31, up 32..63), 4 threads/row, 16 floats
  const int br = tid >> 2;
  const int bc = tid & 3;
  const int grow = (br < TN) ? (nb + br) : (I_ + nb + (br - TN));
  const float* bp = w13e + (size_t)grow * H_ + bc*16;
  const int srow  = (((br < TN) ? 0 : (I_/128)) + (nb >> 7)) * (H_/128);

  // A fragment row pointers (clamped; OOB rows discarded in epilogue)
  const unsigned short* aP[MT_];
  #pragma unroll
  for (int mt = 0; mt < MT_; mt++){
    int sl = off + m0 + wave*(TM/4) + mt*16 + l16;
    sl = min(sl, NPAIR - 1);
    aP[mt] = xg + (size_t)sl * H_ + quad*8;
  }

  f32x4 acc[2][MT_][2];
  #pragma unroll
  for (int h = 0; h < 2; h++)
    #pragma unroll
    for (int mt = 0; mt < MT_; mt++)
      #pragma unroll
      for (int nt = 0; nt < 2; nt++)
        acc[h][mt][nt] = (f32x4){0.f, 0.f, 0.f, 0.f};

  float4 R0[4], R1[4];        // B reg buffers (tiles i+1, i+2)
  bf16x8 A0[2][MT_], A1[2][MT_];
  float  sE, sO;

  auto loadB = [&](int t, float4* R){
    const float* p = bp + t*BK;
    #pragma unroll
    for (int j = 0; j < 4; j++) R[j] = *(const float4*)(p + j*4);
  };
  auto loadA = [&](int t, bf16x8 (*A)[MT_]){
    #pragma unroll
    for (int kk = 0; kk < 2; kk++)
      #pragma unroll
      for (int mt = 0; mt < MT_; mt++)
        A[kk][mt] = *(const bf16x8*)(aP[mt] + t*BK + kk*32);
  };
  auto storeB = [&](const float4* R, float s, int buf){
    u16x8 w0, w1;
    cvt4(w0, 0, R[0], s); cvt4(w0, 4, R[1], s);
    cvt4(w1, 0, R[2], s); cvt4(w1, 4, R[3], s);
    *(u16x8*)&Bs[buf][br][bc*16]     = w0;
    *(u16x8*)&Bs[buf][br][bc*16 + 8] = w1;
  };
  auto mfma = [&](int buf, bf16x8 (*A)[MT_]){
    #pragma unroll
    for (int kk = 0; kk < 2; kk++)
      #pragma unroll
      for (int hh = 0; hh < 2; hh++)
        #pragma unroll
        for (int nt = 0; nt < 2; nt++){
          bf16x8 bv = *(const bf16x8*)&Bs[buf][hh*TN + nt*16 + l16][kk*32 + quad*8];
          #pragma unroll
          for (int mt = 0; mt < MT_; mt++)
            acc[hh][mt][nt] = __builtin_amdgcn_mfma_f32_16x16x32_bf16(A[kk][mt], bv, acc[hh][mt][nt], 0, 0, 0);
        }
  };

  const int NITER = H_/BK;   // 32 (even)
  // prologue
  loadB(0, R0); sE = s13e[srow];
  loadB(1, R1); sO = s13e[srow];
  loadA(0, A0);
  storeB(R0, sE, 0);
  sync_lds();

  for (int i = 0; i < NITER; i += 2){
    if (i+2 < NITER){ loadB(i+2, R0); sE = s13e[srow + ((i+2) >> 1)]; }
    loadA(i+1, A1);
    mfma(0, A0);
    storeB(R1, sO, 1);
    sync_lds();
    if (i+3 < NITER){ loadB(i+3, R1); sO = s13e[srow + ((i+3) >> 1)]; }
    if (i+2 < NITER) loadA(i+2, A0);
    mfma(1, A1);
    if (i+2 < NITER){ storeB(R0, sE, 0); sync_lds(); }
  }

  // epilogue: act = silu(gate)*up
  #pragma unroll
  for (int mt = 0; mt < MT_; mt++){
    #pragma unroll
    for (int nt = 0; nt < 2; nt++){
      #pragma unroll
      for (int r = 0; r < 4; r++){
        const int m = wave*(TM/4) + mt*16 + quad*4 + r;
        if (m < rows){
          const float g = acc[0][mt][nt][r];
          const float u = acc[1][mt][nt][r];
          const float sg = g / (1.f + __expf(-g));
          act[(size_t)(off + m0 + m)*I_ + (nb + nt*16 + l16)] = f2bf(sg * u);
        }
      }
    }
  }
}

// ---------------------------------------------------------------------------
// GEMM2: buf[slot,h] = act @ W2^T (unscaled). Same pipeline.
// grid: (H/TN=64, 6, E=8), block 256.
// ---------------------------------------------------------------------------
__global__ __launch_bounds__(256, 3)
void gemm2_kernel(const unsigned short* __restrict__ act, const float* __restrict__ w2,
                  const float* __restrict__ s2, const int* __restrict__ offs,
                  float* __restrict__ buf)
{
  const int e   = blockIdx.z;
  const int off = offs[e];
  const int cnt = offs[e+1] - off;
  const int m0  = blockIdx.y * TM;
  if (m0 >= cnt) return;
  const int rows = min(TM, cnt - m0);
  const int nb   = blockIdx.x * TN;

  __shared__ __align__(16) unsigned short Bs[2][TN][LDSB];   // 9216 B

  const int tid  = threadIdx.x;
  const int wave = tid >> 6;
  const int lane = tid & 63;
  const int quad = lane >> 4;
  const int l16  = lane & 15;

  const float* w2e = w2 + (size_t)e * H_ * I_;
  const float* s2e = s2 + (size_t)e * (H_/128) * (I_/128);

  // B staging: 8 threads/row, 8 contiguous floats each
  const int br = tid >> 3;                // 0..31
  const int bc = tid & 7;
  const float* bp = w2e + (size_t)(nb + br) * I_ + bc*8;
  const int srow  = (nb >> 7) * (I_/128);

  const unsigned short* aP[MT_];
  #pragma unroll
  for (int mt = 0; mt < MT_; mt++){
    int sl = off + m0 + wave*(TM/4) + mt*16 + l16;
    sl = min(sl, NPAIR - 1);
    aP[mt] = act + (size_t)sl * I_ + quad*8;
  }

  f32x4 acc[MT_][2];
  #pragma unroll
  for (int mt = 0; mt < MT_; mt++)
    #pragma unroll
    for (int nt = 0; nt < 2; nt++)
      acc[mt][nt] = (f32x4){0.f, 0.f, 0.f, 0.f};

  float4 R0[2], R1[2];
  bf16x8 A0[2][MT_], A1[2][MT_];
  float  sE, sO;

  auto loadB = [&](int t, float4* R){
    const float* p = bp + t*BK;
    #pragma unroll
    for (int j = 0; j < 2; j++) R[j] = *(const float4*)(p + j*4);
  };
  auto loadA = [&](int t, bf16x8 (*A)[MT_]){
    #pragma unroll
    for (int kk = 0; kk < 2; kk++)
      #pragma unroll
      for (int mt = 0; mt < MT_; mt++)
        A[kk][mt] = *(const bf16x8*)(aP[mt] + t*BK + kk*32);
  };
  auto storeB = [&](const float4* R, float s, int buf_i){
    u16x8 w0;
    cvt4(w0, 0, R[0], s); cvt4(w0, 4, R[1], s);
    *(u16x8*)&Bs[buf_i][br][bc*8] = w0;
  };
  auto mfma = [&](int buf_i, bf16x8 (*A)[MT_]){
    #pragma unroll
    for (int kk = 0; kk < 2; kk++)
      #pragma unroll
      for (int nt = 0; nt < 2; nt++){
        bf16x8 bv = *(const bf16x8*)&Bs[buf_i][nt*16 + l16][kk*32 + quad*8];
        #pragma unroll
        for (int mt = 0; mt < MT_; mt++)
          acc[mt][nt] = __builtin_amdgcn_mfma_f32_16x16x32_bf16(A[kk][mt], bv, acc[mt][nt], 0, 0, 0);
      }
  };

  const int NITER = I_/BK;   // 44 (even)
  loadB(0, R0); sE = s2e[srow];
  loadB(1, R1); sO = s2e[srow];
  loadA(0, A0);
  storeB(R0, sE, 0);
  sync_lds();

  for (int i = 0; i < NITER; i += 2){
    if (i+2 < NITER){ loadB(i+2, R0); sE = s2e[srow + ((i+2) >> 1)]; }
    loadA(i+1, A1);
    mfma(0, A0);
    storeB(R1, sO, 1);
    sync_lds();
    if (i+3 < NITER){ loadB(i+3, R1); sO = s2e[srow + ((i+3) >> 1)]; }
    if (i+2 < NITER) loadA(i+2, A0);
    mfma(1, A1);
    if (i+2 < NITER){ storeB(R0, sE, 0); sync_lds(); }
  }

  // epilogue: plain stores per slot row
  #pragma unroll
  for (int mt = 0; mt < MT_; mt++){
    #pragma unroll
    for (int nt = 0; nt < 2; nt++){
      #pragma unroll
      for (int r = 0; r < 4; r++){
        const int m = wave*(TM/4) + mt*16 + quad*4 + r;
        if (m < rows)
          buf[(size_t)(off + m0 + m)*H_ + (nb + nt*16 + l16)] = acc[mt][nt][r];
      }
    }
  }
}

// ---------------------------------------------------------------------------
// Combine: out[t,:] = tw[2t]*buf[sop[2t],:] + tw[2t+1]*buf[sop[2t+1],:]
// ---------------------------------------------------------------------------
__global__ void combine_kernel(const float* __restrict__ buf, const int* __restrict__ sop,
                               const float* __restrict__ tw, float* __restrict__ out){
  const int gid = blockIdx.x*256 + threadIdx.x;
  const int t = gid >> 9;
  const int c = gid & 511;
  const int s0 = sop[2*t], s1 = sop[2*t+1];
  const float w0 = tw[2*t], w1 = tw[2*t+1];
  const float4 v0 = ((const float4*)buf)[(size_t)s0*(H_/4) + c];
  const float4 v1 = ((const float4*)buf)[(size_t)s1*(H_/4) + c];
  float4 o;
  o.x = w0*v0.x + w1*v1.x;
  o.y = w0*v0.y + w1*v1.y;
  o.z = w0*v0.z + w1*v1.z;
  o.w = w0*v0.w + w1*v1.w;
  ((float4*)out)[gid] = o;
}

// ---------------------------------------------------------------------------
extern "C" void kernel_launch(void* const* d_in, const int* in_sizes, int n_in,
                              void* d_out, int out_size, void* d_ws, size_t ws_size,
                              hipStream_t stream){
  const float* x   = (const float*)d_in[0];
  const int*   ids = (const int*)  d_in[1];
  const float* tw  = (const float*)d_in[2];
  const float* w13 = (const float*)d_in[3];
  const float* s13 = (const float*)d_in[4];
  const float* w2  = (const float*)d_in[5];
  const float* s2  = (const float*)d_in[6];
  float* out = (float*)d_out;

  char* ws = (char*)d_ws;
  int* offs = (int*)ws;                                   // 9 ints
  int* ptok = (int*)(ws + 64);                            // 1024 ints
  int* sop  = (int*)(ws + 64 + 4096);                     // 1024 ints
  unsigned short* xg  = (unsigned short*)(ws + 16384);    // [1024][H] bf16 (aliased by buf)
  float*          buf = (float*)(ws + 16384);             // [1024][H] f32
  unsigned short* act = (unsigned short*)(ws + 16384 + (size_t)NPAIR*H_*4);  // [1024][I] bf16

  route_kernel  <<<1, NPAIR, 0, stream>>>(ids, offs, ptok, sop);
  prep_kernel   <<<NPAIR, 256, 0, stream>>>(x, ptok, xg);
  gemm1_kernel  <<<dim3(I_/TN, (NPAIR + TM - 1)/TM, E_), 256, 0, stream>>>(xg, w13, s13, offs, act);
  gemm2_kernel  <<<dim3(H_/TN, (NPAIR + TM - 1)/TM, E_), 256, 0, stream>>>(act, w2, s2, offs, buf);
  combine_kernel<<<(T_*H_/4)/256, 256, 0, stream>>>(buf, sop, tw, out);
}